// Round 7
// baseline (165.193 us; speedup 1.0000x reference)
//
#include <hip/hip_runtime.h>
#include <hip/hip_bf16.h>

typedef __bf16 bf16x8 __attribute__((ext_vector_type(8)));
typedef __bf16 bf16x4 __attribute__((ext_vector_type(4)));
typedef float  f32x4  __attribute__((ext_vector_type(4)));

typedef __attribute__((address_space(3))) void lds_void;
typedef __attribute__((address_space(1))) const void gbl_void;

constexpr int SEQ = 2048;
constexpr int HD  = 64;
constexpr int KT  = 64;
constexpr int QB  = 64;      // queries per block (4 waves x 16)
constexpr int NT  = SEQ / KT;   // 32 tiles
constexpr int LDP = 72;      // padded LDS row for P

// =====================================================================
// Prepass: rewrite K and V^T as bf16 in MFMA-FRAGMENT ORDER (linear 8KB
// per tile). Coalesced f32 reads -> LDS -> coalesced bf16x8 frag writes.
//   Kf[bh][t][frag=s*2+kh][lane][8] : lane(lo,hi) = K[t*64+s*16+lo][kh*32+hi*8+j]
//   Vf[bh][t][frag=nt*2+kh][lane][8]: lane(lo,hi) = V[t*64+kh*32+hi*8+j][nt*16+lo]
// =====================================================================
__global__ __launch_bounds__(256)
void prepass(const float* __restrict__ K, const float* __restrict__ V,
             __bf16* __restrict__ Kf, __bf16* __restrict__ Vf)
{
    __shared__ __bf16 Kt[64][72];
    __shared__ __bf16 Vt[64][72];

    const int t = blockIdx.x, bh = blockIdx.y, tid = threadIdx.x;
    const size_t base = (size_t)bh * SEQ * HD + (size_t)t * 64 * HD;

    #pragma unroll
    for (int p = 0; p < 4; ++p) {
        int idx = p * 256 + tid;
        int row = idx >> 4, c4 = (idx & 15) * 4;
        float4 kv = *(const float4*)(K + base + row * HD + c4);
        bf16x4 kb;
        kb[0]=(__bf16)kv.x; kb[1]=(__bf16)kv.y; kb[2]=(__bf16)kv.z; kb[3]=(__bf16)kv.w;
        *(bf16x4*)&Kt[row][c4] = kb;
        float4 vv = *(const float4*)(V + base + row * HD + c4);
        bf16x4 vb;
        vb[0]=(__bf16)vv.x; vb[1]=(__bf16)vv.y; vb[2]=(__bf16)vv.z; vb[3]=(__bf16)vv.w;
        *(bf16x4*)&Vt[row][c4] = vb;
    }
    __syncthreads();

    __bf16* kd = Kf + (size_t)(bh * NT + t) * 4096;
    __bf16* vd = Vf + (size_t)(bh * NT + t) * 4096;
    #pragma unroll
    for (int p = 0; p < 2; ++p) {
        int gran = p * 256 + tid;
        int frag = gran >> 6, l = gran & 63, lo = l & 15, hi = l >> 4;
        int s = frag >> 1, kh = frag & 1;
        bf16x8 ko = *(const bf16x8*)&Kt[s*16 + lo][kh*32 + hi*8];
        *(bf16x8*)(kd + gran * 8) = ko;
        bf16x8 vo;
        #pragma unroll
        for (int j = 0; j < 8; ++j)
            vo[j] = Vt[kh*32 + hi*8 + j][s*16 + lo];
        *(bf16x8*)(vd + gran * 8) = vo;
    }
}

// =====================================================================
// Main: flash attention. K/V tiles staged ONCE per block into LDS
// (shared by 4 waves -> 4x less L2 traffic), double-buffered
// global_load_lds, one barrier per tile. Swapped QK^T, in-lane softmax,
// T13 defer-max, packed P stores, setprio around MFMA clusters.
// =====================================================================
__global__ __launch_bounds__(256, 3)
void attn_fwd4(const float* __restrict__ Q, const __bf16* __restrict__ Kf,
               const __bf16* __restrict__ Vf, const int* __restrict__ mask,
               float* __restrict__ out)
{
    __shared__ __bf16 Kl[2][4096];             // 8KB per buf, fragment-linear
    __shared__ __bf16 Vl[2][4096];
    __shared__ __bf16 Pl[4][16][LDP];          // per-wave P tile [q][key]
    __shared__ unsigned long long Ml[NT];      // 2048 mask bits

    const int tid = threadIdx.x;
    const int w   = tid >> 6;
    const int l   = tid & 63;
    const int lo  = l & 15;
    const int hi  = l >> 4;

    const int id   = blockIdx.x;                   // 0..1023
    const int virt = (id & 7) * 128 + (id >> 3);   // XCD-contiguous
    const int bh   = virt >> 5;
    const int qb   = virt & 31;
    const int b    = bh >> 4;
    const size_t base = (size_t)bh * SEQ * HD;
    const int qbase = qb * QB + w * 16;

    // ---- pack mask -> bits (8 keys/thread)
    {
        const int4* mp = (const int4*)(mask + b * SEQ);
        int4 m0 = mp[tid * 2], m1 = mp[tid * 2 + 1];
        unsigned byte =
            ((unsigned)(m0.x != 0)     ) | ((unsigned)(m0.y != 0) << 1) |
            ((unsigned)(m0.z != 0) << 2) | ((unsigned)(m0.w != 0) << 3) |
            ((unsigned)(m1.x != 0) << 4) | ((unsigned)(m1.y != 0) << 5) |
            ((unsigned)(m1.z != 0) << 6) | ((unsigned)(m1.w != 0) << 7);
        ((unsigned char*)Ml)[tid] = (unsigned char)byte;
    }

    // ---- Q fragments (B operand): q = qbase+lo, k(d) = kh*32 + hi*8 + i
    bf16x8 qf[2];
    {
        const float* qp = Q + base + (size_t)(qbase + lo) * HD;
        #pragma unroll
        for (int kh = 0; kh < 2; ++kh) {
            const float4 a = *(const float4*)(qp + kh*32 + hi*8);
            const float4 c = *(const float4*)(qp + kh*32 + hi*8 + 4);
            bf16x8 f;
            f[0]=(__bf16)a.x; f[1]=(__bf16)a.y; f[2]=(__bf16)a.z; f[3]=(__bf16)a.w;
            f[4]=(__bf16)c.x; f[5]=(__bf16)c.y; f[6]=(__bf16)c.z; f[7]=(__bf16)c.w;
            qf[kh] = f;
        }
    }

    const __bf16* Ksrc = Kf + (size_t)bh * NT * 4096;
    const __bf16* Vsrc = Vf + (size_t)bh * NT * 4096;

    // stage one tile (K 8KB + V 8KB) via global_load_lds width 16
    auto stage = [&](int buf, int t) {
        const __bf16* kg = Ksrc + (size_t)t * 4096;
        const __bf16* vg = Vsrc + (size_t)t * 4096;
        #pragma unroll
        for (int r = 0; r < 2; ++r) {
            __builtin_amdgcn_global_load_lds(
                (gbl_void*)(kg + (size_t)(r*256 + tid) * 8),
                (lds_void*)(&Kl[buf][0] + (r*256 + w*64) * 8), 16, 0, 0);
            __builtin_amdgcn_global_load_lds(
                (gbl_void*)(vg + (size_t)(r*256 + tid) * 8),
                (lds_void*)(&Vl[buf][0] + (r*256 + w*64) * 8), 16, 0, 0);
        }
    };

    f32x4 acc[4] = {{0,0,0,0},{0,0,0,0},{0,0,0,0},{0,0,0,0}};
    float m_run  = -INFINITY;
    float l_part = 0.f;         // per-lane partial row sum

    stage(0, 0);
    __syncthreads();   // vmcnt(0) drained: tile 0 + Ml ready

    for (int t = 0; t < NT; ++t) {
        const int buf = t & 1;
        if (t + 1 < NT) stage(buf ^ 1, t + 1);   // prefetch under compute

        // ---- QK^T swapped: sv[s][r] = S^T[key=s*16+hi*4+r][q=lo]
        float sv[4][4];
        const unsigned long long mb = Ml[t];
        __builtin_amdgcn_s_setprio(1);
        #pragma unroll
        for (int s = 0; s < 4; ++s) {
            bf16x8 k0 = *(const bf16x8*)&Kl[buf][(s*2+0) * 512 + l*8];
            bf16x8 k1 = *(const bf16x8*)&Kl[buf][(s*2+1) * 512 + l*8];
            f32x4 c = {0,0,0,0};
            c = __builtin_amdgcn_mfma_f32_16x16x32_bf16(k0, qf[0], c, 0, 0, 0);
            c = __builtin_amdgcn_mfma_f32_16x16x32_bf16(k1, qf[1], c, 0, 0, 0);
            const unsigned ms = (unsigned)(mb >> (s * 16));
            #pragma unroll
            for (int r = 0; r < 4; ++r)
                sv[s][r] = c[r] * 0.03125f +
                           (((ms >> (hi*4 + r)) & 1u) ? 0.f : -1e9f);
        }
        __builtin_amdgcn_s_setprio(0);

        // ---- V fragment loads issued early (independent of softmax)
        bf16x8 vfr[8];
        #pragma unroll
        for (int f = 0; f < 8; ++f)
            vfr[f] = *(const bf16x8*)&Vl[buf][f * 512 + l*8];

        // ---- T13 defer-max
        float pm = sv[0][0];
        #pragma unroll
        for (int s = 0; s < 4; ++s)
            #pragma unroll
            for (int r = 0; r < 4; ++r)
                pm = fmaxf(pm, sv[s][r]);

        if (!__all(pm - m_run <= 8.0f)) {
            float pmr = pm;
            pmr = fmaxf(pmr, __shfl_xor(pmr, 16));
            pmr = fmaxf(pmr, __shfl_xor(pmr, 32));
            const float mn  = fmaxf(m_run, pmr);
            const float scl = __expf(m_run - mn);
            m_run = mn;
            l_part *= scl;
            #pragma unroll
            for (int nt = 0; nt < 4; ++nt)
                #pragma unroll
                for (int r = 0; r < 4; ++r)
                    acc[nt][r] *= scl;
        }

        // ---- P = exp(S - m_run), per-lane partial sum
        float p[4][4], ls = 0.f;
        #pragma unroll
        for (int s = 0; s < 4; ++s) {
            #pragma unroll
            for (int r = 0; r < 4; ++r) {
                p[s][r] = __expf(sv[s][r] - m_run);
                ls += p[s][r];
            }
        }
        l_part += ls;

        // ---- packed P^T store: 4x ds_write_b64
        #pragma unroll
        for (int s = 0; s < 4; ++s) {
            bf16x4 pk;
            pk[0]=(__bf16)p[s][0]; pk[1]=(__bf16)p[s][1];
            pk[2]=(__bf16)p[s][2]; pk[3]=(__bf16)p[s][3];
            *(bf16x4*)&Pl[w][lo][s*16 + hi*4] = pk;
        }

        // ---- PV: O^T = V^T · P^T
        bf16x8 pa0 = *(const bf16x8*)&Pl[w][lo][hi * 8];
        bf16x8 pa1 = *(const bf16x8*)&Pl[w][lo][32 + hi * 8];
        __builtin_amdgcn_s_setprio(1);
        #pragma unroll
        for (int nt = 0; nt < 4; ++nt) {
            acc[nt] = __builtin_amdgcn_mfma_f32_16x16x32_bf16(vfr[nt*2+0], pa0, acc[nt], 0, 0, 0);
            acc[nt] = __builtin_amdgcn_mfma_f32_16x16x32_bf16(vfr[nt*2+1], pa1, acc[nt], 0, 0, 0);
        }
        __builtin_amdgcn_s_setprio(0);

        __syncthreads();   // all waves done with buf; next tile landed
    }

    // ---- epilogue
    float lr = l_part;
    lr += __shfl_xor(lr, 16);
    lr += __shfl_xor(lr, 32);
    const float inv = 1.0f / lr;

    float* op = out + base + (size_t)(qbase + lo) * HD;
    #pragma unroll
    for (int nt = 0; nt < 4; ++nt)
        #pragma unroll
        for (int r = 0; r < 4; ++r)
            op[nt*16 + hi*4 + r] = acc[nt][r] * inv;
}

// =====================================================================
// Fallback (round-2, passing) if ws_size is too small.
// =====================================================================
__global__ __launch_bounds__(256)
void attn_fwd_legacy(const float* __restrict__ Q, const float* __restrict__ K,
                     const float* __restrict__ V, const int* __restrict__ mask,
                     float* __restrict__ out)
{
    __shared__ __bf16 Kl[KT][LDP];
    __shared__ __bf16 Vl[HD][LDP];
    __shared__ __bf16 Pl[4][16][LDP];

    const int tid = threadIdx.x;
    const int w   = tid >> 6;
    const int l   = tid & 63;
    const int lo  = l & 15;
    const int hi  = l >> 4;

    const int bh = blockIdx.y;
    const int b  = bh >> 4;
    const size_t base = (size_t)bh * SEQ * HD;
    const int qbase = blockIdx.x * QB + w * 16;

    bf16x8 qf[2];
    {
        const float* qp = Q + base + (size_t)(qbase + lo) * HD;
        #pragma unroll
        for (int kh = 0; kh < 2; ++kh) {
            const float4 a = *(const float4*)(qp + kh*32 + hi*8);
            const float4 c = *(const float4*)(qp + kh*32 + hi*8 + 4);
            bf16x8 f;
            f[0]=(__bf16)a.x; f[1]=(__bf16)a.y; f[2]=(__bf16)a.z; f[3]=(__bf16)a.w;
            f[4]=(__bf16)c.x; f[5]=(__bf16)c.y; f[6]=(__bf16)c.z; f[7]=(__bf16)c.w;
            qf[kh] = f;
        }
    }

    f32x4 acc[4] = {{0,0,0,0},{0,0,0,0},{0,0,0,0},{0,0,0,0}};
    float m_run[4], l_run[4];
    #pragma unroll
    for (int r = 0; r < 4; ++r) { m_run[r] = -INFINITY; l_run[r] = 0.f; }

    const int* maskp = mask + b * SEQ;

    for (int k0 = 0; k0 < SEQ; k0 += KT) {
        #pragma unroll
        for (int i = 0; i < 4; ++i) {
            int e4 = i * 256 + tid;
            int key = e4 >> 4, d4 = (e4 & 15) * 4;
            float4 kv = *(const float4*)(K + base + (size_t)(k0 + key) * HD + d4);
            bf16x4 kb;
            kb[0]=(__bf16)kv.x; kb[1]=(__bf16)kv.y; kb[2]=(__bf16)kv.z; kb[3]=(__bf16)kv.w;
            *(bf16x4*)&Kl[key][d4] = kb;
        }
        #pragma unroll
        for (int i = 0; i < 4; ++i) {
            int e4 = i * 256 + tid;
            int key = e4 >> 4, d4 = (e4 & 15) * 4;
            float4 vv = *(const float4*)(V + base + (size_t)(k0 + key) * HD + d4);
            Vl[d4+0][key] = (__bf16)vv.x;
            Vl[d4+1][key] = (__bf16)vv.y;
            Vl[d4+2][key] = (__bf16)vv.z;
            Vl[d4+3][key] = (__bf16)vv.w;
        }
        __syncthreads();

        float sv[4][4];
        #pragma unroll
        for (int s = 0; s < 4; ++s) {
            f32x4 c = {0,0,0,0};
            bf16x8 kf0 = *(const bf16x8*)&Kl[s*16 + lo][hi*8];
            bf16x8 kf1 = *(const bf16x8*)&Kl[s*16 + lo][32 + hi*8];
            c = __builtin_amdgcn_mfma_f32_16x16x32_bf16(qf[0], kf0, c, 0, 0, 0);
            c = __builtin_amdgcn_mfma_f32_16x16x32_bf16(qf[1], kf1, c, 0, 0, 0);
            const int km = maskp[k0 + s*16 + lo];
            #pragma unroll
            for (int r = 0; r < 4; ++r)
                sv[s][r] = km ? (c[r] * 0.03125f) : -1e9f;
        }

        float tm[4];
        #pragma unroll
        for (int r = 0; r < 4; ++r)
            tm[r] = fmaxf(fmaxf(sv[0][r], sv[1][r]), fmaxf(sv[2][r], sv[3][r]));
        #pragma unroll
        for (int off = 1; off < 16; off <<= 1)
            #pragma unroll
            for (int r = 0; r < 4; ++r)
                tm[r] = fmaxf(tm[r], __shfl_xor(tm[r], off));

        float scl[4];
        #pragma unroll
        for (int r = 0; r < 4; ++r) {
            float mn = fmaxf(m_run[r], tm[r]);
            scl[r] = __expf(m_run[r] - mn);
            m_run[r] = mn;
        }
        float pv_[4][4], rs[4] = {0.f, 0.f, 0.f, 0.f};
        #pragma unroll
        for (int s = 0; s < 4; ++s)
            #pragma unroll
            for (int r = 0; r < 4; ++r) {
                float p = __expf(sv[s][r] - m_run[r]);
                pv_[s][r] = p;
                rs[r] += p;
            }
        #pragma unroll
        for (int off = 1; off < 16; off <<= 1)
            #pragma unroll
            for (int r = 0; r < 4; ++r)
                rs[r] += __shfl_xor(rs[r], off);
        #pragma unroll
        for (int r = 0; r < 4; ++r)
            l_run[r] = l_run[r] * scl[r] + rs[r];
        #pragma unroll
        for (int nt = 0; nt < 4; ++nt)
            #pragma unroll
            for (int r = 0; r < 4; ++r)
                acc[nt][r] *= scl[r];

        #pragma unroll
        for (int s = 0; s < 4; ++s)
            #pragma unroll
            for (int r = 0; r < 4; ++r)
                Pl[w][hi*4 + r][s*16 + lo] = (__bf16)pv_[s][r];

        bf16x8 pa0 = *(const bf16x8*)&Pl[w][lo][hi*8];
        bf16x8 pa1 = *(const bf16x8*)&Pl[w][lo][32 + hi*8];
        #pragma unroll
        for (int nt = 0; nt < 4; ++nt) {
            bf16x8 v0 = *(const bf16x8*)&Vl[nt*16 + lo][hi*8];
            bf16x8 v1 = *(const bf16x8*)&Vl[nt*16 + lo][32 + hi*8];
            acc[nt] = __builtin_amdgcn_mfma_f32_16x16x32_bf16(pa0, v0, acc[nt], 0, 0, 0);
            acc[nt] = __builtin_amdgcn_mfma_f32_16x16x32_bf16(pa1, v1, acc[nt], 0, 0, 0);
        }
        __syncthreads();
    }

    float inv[4];
    #pragma unroll
    for (int r = 0; r < 4; ++r) inv[r] = 1.0f / l_run[r];
    float* op = out + base + (size_t)qbase * HD;
    #pragma unroll
    for (int nt = 0; nt < 4; ++nt)
        #pragma unroll
        for (int r = 0; r < 4; ++r)
            op[(size_t)(hi*4 + r) * HD + nt*16 + lo] = acc[nt][r] * inv[r];
}

extern "C" void kernel_launch(void* const* d_in, const int* in_sizes, int n_in,
                              void* d_out, int out_size, void* d_ws, size_t ws_size,
                              hipStream_t stream) {
    (void)in_sizes; (void)n_in; (void)out_size;
    const float* Q  = (const float*)d_in[0];
    const float* K  = (const float*)d_in[1];
    const float* V  = (const float*)d_in[2];
    const int* mask = (const int*)d_in[3];
    float* out      = (float*)d_out;

    const size_t kv_elems = (size_t)32 * SEQ * HD;          // per tensor
    const size_t need = kv_elems * 2 /*bf16*/ * 2 /*K+V*/;  // 16.78 MB

    if (ws_size >= need) {
        __bf16* Kf = (__bf16*)d_ws;
        __bf16* Vf = Kf + kv_elems;
        hipLaunchKernelGGL(prepass, dim3(NT, 32), dim3(256), 0, stream, K, V, Kf, Vf);
        hipLaunchKernelGGL(attn_fwd4, dim3(1024), dim3(256), 0, stream,
                           Q, Kf, Vf, mask, out);
    } else {
        hipLaunchKernelGGL(attn_fwd_legacy, dim3(SEQ / QB, 32), dim3(256), 0, stream,
                           Q, K, V, mask, out);
    }
}

// Round 9
// 144.146 us; speedup vs baseline: 1.1460x; 1.1460x over previous
//
#include <hip/hip_runtime.h>
#include <hip/hip_bf16.h>

typedef __bf16 bf16x8 __attribute__((ext_vector_type(8)));
typedef __bf16 bf16x4 __attribute__((ext_vector_type(4)));
typedef float  f32x4  __attribute__((ext_vector_type(4)));

typedef __attribute__((address_space(3))) void lds_void;
typedef __attribute__((address_space(1))) const void gbl_void;

constexpr int SEQ = 2048;
constexpr int HD  = 64;
constexpr int KT  = 64;
constexpr int QB  = 64;
constexpr int NT  = SEQ / KT;   // 32 tiles
constexpr int LDP = 72;
constexpr float QSCL = 0.03125f;   // 1/sqrt(1024)

// =====================================================================
// Prepass: K / V^T -> bf16 MFMA-fragment order (linear 8KB per tile).
//  * K rows PERMUTED (krow) so PV's B-fragment equals the lane-local
//    QK^T output: P never leaves registers in the main kernel.
//  * V rows of masked keys zeroed (mask applied via V, not scores).
//   Kf[bh][t][frag=s*2+kh][lane][8] = K[t*64+krow(s,lo)][kh*32+hi*8+j]
//   Vf[bh][t][frag=n*2+kh][lane][8] = V[t*64+kh*32+hi*8+j][n*16+lo]
// =====================================================================
__global__ __launch_bounds__(256)
void prepass(const float* __restrict__ K, const float* __restrict__ V,
             const int* __restrict__ mask,
             __bf16* __restrict__ Kf, __bf16* __restrict__ Vf)
{
    __shared__ __bf16 Kt[64][72];
    __shared__ __bf16 Vt[64][72];

    const int t = blockIdx.x, bh = blockIdx.y, tid = threadIdx.x;
    const int b = bh >> 4;
    const size_t base = (size_t)bh * SEQ * HD + (size_t)t * 64 * HD;
    const int* maskp = mask + b * SEQ + t * 64;

    #pragma unroll
    for (int p = 0; p < 4; ++p) {
        int idx = p * 256 + tid;
        int row = idx >> 4, c4 = (idx & 15) * 4;
        float4 kv = *(const float4*)(K + base + row * HD + c4);
        bf16x4 kb;
        kb[0]=(__bf16)kv.x; kb[1]=(__bf16)kv.y; kb[2]=(__bf16)kv.z; kb[3]=(__bf16)kv.w;
        *(bf16x4*)&Kt[row][c4] = kb;
        const float m01 = maskp[row] ? 1.0f : 0.0f;   // mask -> V
        float4 vv = *(const float4*)(V + base + row * HD + c4);
        bf16x4 vb;
        vb[0]=(__bf16)(vv.x*m01); vb[1]=(__bf16)(vv.y*m01);
        vb[2]=(__bf16)(vv.z*m01); vb[3]=(__bf16)(vv.w*m01);
        *(bf16x4*)&Vt[row][c4] = vb;
    }
    __syncthreads();

    __bf16* kd = Kf + (size_t)(bh * NT + t) * 4096;
    __bf16* vd = Vf + (size_t)(bh * NT + t) * 4096;
    #pragma unroll
    for (int p = 0; p < 2; ++p) {
        int gran = p * 256 + tid;
        int frag = gran >> 6, l = gran & 63, lo = l & 15, hi = l >> 4;
        int s = frag >> 1, kh = frag & 1;
        // permuted key row: makes PV B-frag == in-lane QK^T output
        int krow = 32*(s>>1) + 8*(lo>>2) + 4*(s&1) + (lo&3);
        bf16x8 ko = *(const bf16x8*)&Kt[krow][kh*32 + hi*8];
        *(bf16x8*)(kd + gran * 8) = ko;
        bf16x8 vo;
        #pragma unroll
        for (int j = 0; j < 8; ++j)
            vo[j] = Vt[kh*32 + hi*8 + j][s*16 + lo];
        *(bf16x8*)(vd + gran * 8) = vo;
    }
}

// =====================================================================
// Main: flash attention. P fully in-register (key-permuted K), mask via
// zeroed V + l from mask01-MFMA, Q pre-scaled, defer-max, dbuf staging.
// =====================================================================
__global__ __launch_bounds__(256, 4)
void attn_fwd5(const float* __restrict__ Q, const __bf16* __restrict__ Kf,
               const __bf16* __restrict__ Vf, const int* __restrict__ mask,
               float* __restrict__ out)
{
    __shared__ __bf16 Kl[2][4096];
    __shared__ __bf16 Vl[2][4096];
    __shared__ __attribute__((aligned(16))) __bf16 Ml16[SEQ];  // mask01 bf16

    const int tid = threadIdx.x;
    const int w   = tid >> 6;
    const int l   = tid & 63;
    const int lo  = l & 15;
    const int hi  = l >> 4;

    const int id   = blockIdx.x;                   // 0..1023
    const int virt = (id & 7) * 128 + (id >> 3);   // XCD-contiguous
    const int bh   = virt >> 5;
    const int qb   = virt & 31;
    const int b    = bh >> 4;
    const size_t base = (size_t)bh * SEQ * HD;
    const int qbase = qb * QB + w * 16;

    // ---- mask -> bf16 0/1 table in LDS (8 keys/thread)
    {
        const int4* mp = (const int4*)(mask + b * SEQ);
        int4 m0 = mp[tid * 2], m1 = mp[tid * 2 + 1];
        bf16x8 mm;
        mm[0]=(__bf16)(m0.x?1.0f:0.0f); mm[1]=(__bf16)(m0.y?1.0f:0.0f);
        mm[2]=(__bf16)(m0.z?1.0f:0.0f); mm[3]=(__bf16)(m0.w?1.0f:0.0f);
        mm[4]=(__bf16)(m1.x?1.0f:0.0f); mm[5]=(__bf16)(m1.y?1.0f:0.0f);
        mm[6]=(__bf16)(m1.z?1.0f:0.0f); mm[7]=(__bf16)(m1.w?1.0f:0.0f);
        *(bf16x8*)&Ml16[tid * 8] = mm;
    }

    // ---- Q fragment (B operand), pre-scaled by 1/32 (exact in bf16)
    bf16x8 qf[2];
    {
        const float* qp = Q + base + (size_t)(qbase + lo) * HD;
        #pragma unroll
        for (int kh = 0; kh < 2; ++kh) {
            const float4 a = *(const float4*)(qp + kh*32 + hi*8);
            const float4 c = *(const float4*)(qp + kh*32 + hi*8 + 4);
            bf16x8 f;
            f[0]=(__bf16)(a.x*QSCL); f[1]=(__bf16)(a.y*QSCL);
            f[2]=(__bf16)(a.z*QSCL); f[3]=(__bf16)(a.w*QSCL);
            f[4]=(__bf16)(c.x*QSCL); f[5]=(__bf16)(c.y*QSCL);
            f[6]=(__bf16)(c.z*QSCL); f[7]=(__bf16)(c.w*QSCL);
            qf[kh] = f;
        }
    }

    const __bf16* Ksrc = Kf + (size_t)bh * NT * 4096;
    const __bf16* Vsrc = Vf + (size_t)bh * NT * 4096;

    auto stage = [&](int buf, int t) {
        const __bf16* kg = Ksrc + (size_t)t * 4096;
        const __bf16* vg = Vsrc + (size_t)t * 4096;
        #pragma unroll
        for (int r = 0; r < 2; ++r) {
            __builtin_amdgcn_global_load_lds(
                (gbl_void*)(kg + (size_t)(r*256 + tid) * 8),
                (lds_void*)(&Kl[buf][0] + (r*256 + w*64) * 8), 16, 0, 0);
            __builtin_amdgcn_global_load_lds(
                (gbl_void*)(vg + (size_t)(r*256 + tid) * 8),
                (lds_void*)(&Vl[buf][0] + (r*256 + w*64) * 8), 16, 0, 0);
        }
    };

    f32x4 acc[4] = {{0,0,0,0},{0,0,0,0},{0,0,0,0},{0,0,0,0}};
    f32x4 acc_l  = {0,0,0,0};      // l (softmax denom) via mask01-MFMA
    float m_run  = -INFINITY;

    stage(0, 0);
    __syncthreads();   // tile 0 + Ml16 ready

    for (int t = 0; t < NT; ++t) {
        const int buf = t & 1;
        if (t + 1 < NT) stage(buf ^ 1, t + 1);   // prefetch under compute

        // ---- QK^T (keys pre-permuted; no scale, no mask)
        f32x4 sc[4];
        __builtin_amdgcn_s_setprio(1);
        #pragma unroll
        for (int s = 0; s < 4; ++s) {
            bf16x8 k0 = *(const bf16x8*)&Kl[buf][(s*2+0) * 512 + l*8];
            bf16x8 k1 = *(const bf16x8*)&Kl[buf][(s*2+1) * 512 + l*8];
            f32x4 c = {0,0,0,0};
            c = __builtin_amdgcn_mfma_f32_16x16x32_bf16(k0, qf[0], c, 0, 0, 0);
            c = __builtin_amdgcn_mfma_f32_16x16x32_bf16(k1, qf[1], c, 0, 0, 0);
            sc[s] = c;
        }
        __builtin_amdgcn_s_setprio(0);

        // ---- V + mask01 fragments (independent of softmax)
        bf16x8 vfr[8];
        #pragma unroll
        for (int f = 0; f < 8; ++f)
            vfr[f] = *(const bf16x8*)&Vl[buf][f * 512 + l*8];
        bf16x8 am0 = *(const bf16x8*)&Ml16[t*64 + hi*8];
        bf16x8 am1 = *(const bf16x8*)&Ml16[t*64 + 32 + hi*8];

        // ---- T13 defer-max (max may include masked scores: harmless)
        float t0 = fmaxf(fmaxf(sc[0][0], sc[0][1]), fmaxf(sc[0][2], sc[0][3]));
        float t1 = fmaxf(fmaxf(sc[1][0], sc[1][1]), fmaxf(sc[1][2], sc[1][3]));
        float t2 = fmaxf(fmaxf(sc[2][0], sc[2][1]), fmaxf(sc[2][2], sc[2][3]));
        float t3 = fmaxf(fmaxf(sc[3][0], sc[3][1]), fmaxf(sc[3][2], sc[3][3]));
        float pm = fmaxf(fmaxf(t0, t1), fmaxf(t2, t3));

        if (!__all(pm - m_run <= 8.0f)) {
            float pmr = pm;
            pmr = fmaxf(pmr, __shfl_xor(pmr, 16));
            pmr = fmaxf(pmr, __shfl_xor(pmr, 32));
            const float mn  = fmaxf(m_run, pmr);
            const float scl = __expf(m_run - mn);
            m_run = mn;
            acc_l[0] *= scl;
            #pragma unroll
            for (int nt = 0; nt < 4; ++nt)
                #pragma unroll
                for (int r = 0; r < 4; ++r)
                    acc[nt][r] *= scl;
        }

        // ---- P = exp(S - m), packed in-lane (key permutation makes
        //      pa_kh[j] == key kh*32 + hi*8 + j : the PV B-fragment)
        bf16x8 pa0, pa1;
        #pragma unroll
        for (int s = 0; s < 4; ++s) {
            #pragma unroll
            for (int r = 0; r < 4; ++r) {
                float pv = __expf(sc[s][r] - m_run);
                if (s < 2) pa0[(s & 1) * 4 + r] = (__bf16)pv;
                else       pa1[(s & 1) * 4 + r] = (__bf16)pv;
            }
        }

        // ---- PV + l accumulation (mask01 row gives denominator)
        __builtin_amdgcn_s_setprio(1);
        #pragma unroll
        for (int nt = 0; nt < 4; ++nt) {
            acc[nt] = __builtin_amdgcn_mfma_f32_16x16x32_bf16(vfr[nt*2+0], pa0, acc[nt], 0, 0, 0);
            acc[nt] = __builtin_amdgcn_mfma_f32_16x16x32_bf16(vfr[nt*2+1], pa1, acc[nt], 0, 0, 0);
        }
        acc_l = __builtin_amdgcn_mfma_f32_16x16x32_bf16(am0, pa0, acc_l, 0, 0, 0);
        acc_l = __builtin_amdgcn_mfma_f32_16x16x32_bf16(am1, pa1, acc_l, 0, 0, 0);
        __builtin_amdgcn_s_setprio(0);

        __syncthreads();   // all waves done with buf; next tile landed
    }

    // ---- epilogue: every lane already holds l for q=lo in acc_l[0]
    const float inv = 1.0f / acc_l[0];
    float* op = out + base + (size_t)(qbase + lo) * HD;
    #pragma unroll
    for (int nt = 0; nt < 4; ++nt)
        #pragma unroll
        for (int r = 0; r < 4; ++r)
            op[nt*16 + hi*4 + r] = acc[nt][r] * inv;
}

// =====================================================================
// Fallback (round-2, passing) if ws_size is too small.
// =====================================================================
__global__ __launch_bounds__(256)
void attn_fwd_legacy(const float* __restrict__ Q, const float* __restrict__ K,
                     const float* __restrict__ V, const int* __restrict__ mask,
                     float* __restrict__ out)
{
    __shared__ __bf16 Kl[KT][LDP];
    __shared__ __bf16 Vl[HD][LDP];
    __shared__ __bf16 Pl[4][16][LDP];

    const int tid = threadIdx.x;
    const int w   = tid >> 6;
    const int l   = tid & 63;
    const int lo  = l & 15;
    const int hi  = l >> 4;

    const int bh = blockIdx.y;
    const int b  = bh >> 4;
    const size_t base = (size_t)bh * SEQ * HD;
    const int qbase = blockIdx.x * QB + w * 16;

    bf16x8 qf[2];
    {
        const float* qp = Q + base + (size_t)(qbase + lo) * HD;
        #pragma unroll
        for (int kh = 0; kh < 2; ++kh) {
            const float4 a = *(const float4*)(qp + kh*32 + hi*8);
            const float4 c = *(const float4*)(qp + kh*32 + hi*8 + 4);
            bf16x8 f;
            f[0]=(__bf16)a.x; f[1]=(__bf16)a.y; f[2]=(__bf16)a.z; f[3]=(__bf16)a.w;
            f[4]=(__bf16)c.x; f[5]=(__bf16)c.y; f[6]=(__bf16)c.z; f[7]=(__bf16)c.w;
            qf[kh] = f;
        }
    }

    f32x4 acc[4] = {{0,0,0,0},{0,0,0,0},{0,0,0,0},{0,0,0,0}};
    float m_run[4], l_run[4];
    #pragma unroll
    for (int r = 0; r < 4; ++r) { m_run[r] = -INFINITY; l_run[r] = 0.f; }

    const int* maskp = mask + b * SEQ;

    for (int k0 = 0; k0 < SEQ; k0 += KT) {
        #pragma unroll
        for (int i = 0; i < 4; ++i) {
            int e4 = i * 256 + tid;
            int key = e4 >> 4, d4 = (e4 & 15) * 4;
            float4 kv = *(const float4*)(K + base + (size_t)(k0 + key) * HD + d4);
            bf16x4 kb;
            kb[0]=(__bf16)kv.x; kb[1]=(__bf16)kv.y; kb[2]=(__bf16)kv.z; kb[3]=(__bf16)kv.w;
            *(bf16x4*)&Kl[key][d4] = kb;
        }
        #pragma unroll
        for (int i = 0; i < 4; ++i) {
            int e4 = i * 256 + tid;
            int key = e4 >> 4, d4 = (e4 & 15) * 4;
            float4 vv = *(const float4*)(V + base + (size_t)(k0 + key) * HD + d4);
            Vl[d4+0][key] = (__bf16)vv.x;
            Vl[d4+1][key] = (__bf16)vv.y;
            Vl[d4+2][key] = (__bf16)vv.z;
            Vl[d4+3][key] = (__bf16)vv.w;
        }
        __syncthreads();

        float sv[4][4];
        #pragma unroll
        for (int s = 0; s < 4; ++s) {
            f32x4 c = {0,0,0,0};
            bf16x8 kf0 = *(const bf16x8*)&Kl[s*16 + lo][hi*8];
            bf16x8 kf1 = *(const bf16x8*)&Kl[s*16 + lo][32 + hi*8];
            c = __builtin_amdgcn_mfma_f32_16x16x32_bf16(qf[0], kf0, c, 0, 0, 0);
            c = __builtin_amdgcn_mfma_f32_16x16x32_bf16(qf[1], kf1, c, 0, 0, 0);
            const int km = maskp[k0 + s*16 + lo];
            #pragma unroll
            for (int r = 0; r < 4; ++r)
                sv[s][r] = km ? (c[r] * 0.03125f) : -1e9f;
        }

        float tm[4];
        #pragma unroll
        for (int r = 0; r < 4; ++r)
            tm[r] = fmaxf(fmaxf(sv[0][r], sv[1][r]), fmaxf(sv[2][r], sv[3][r]));
        #pragma unroll
        for (int off = 1; off < 16; off <<= 1)
            #pragma unroll
            for (int r = 0; r < 4; ++r)
                tm[r] = fmaxf(tm[r], __shfl_xor(tm[r], off));

        float scl[4];
        #pragma unroll
        for (int r = 0; r < 4; ++r) {
            float mn = fmaxf(m_run[r], tm[r]);
            scl[r] = __expf(m_run[r] - mn);
            m_run[r] = mn;
        }
        float pv_[4][4], rs[4] = {0.f, 0.f, 0.f, 0.f};
        #pragma unroll
        for (int s = 0; s < 4; ++s)
            #pragma unroll
            for (int r = 0; r < 4; ++r) {
                float p = __expf(sv[s][r] - m_run[r]);
                pv_[s][r] = p;
                rs[r] += p;
            }
        #pragma unroll
        for (int off = 1; off < 16; off <<= 1)
            #pragma unroll
            for (int r = 0; r < 4; ++r)
                rs[r] += __shfl_xor(rs[r], off);
        #pragma unroll
        for (int r = 0; r < 4; ++r)
            l_run[r] = l_run[r] * scl[r] + rs[r];
        #pragma unroll
        for (int nt = 0; nt < 4; ++nt)
            #pragma unroll
            for (int r = 0; r < 4; ++r)
                acc[nt][r] *= scl[r];

        #pragma unroll
        for (int s = 0; s < 4; ++s)
            #pragma unroll
            for (int r = 0; r < 4; ++r)
                Pl[w][hi*4 + r][s*16 + lo] = (__bf16)pv_[s][r];

        bf16x8 pa0 = *(const bf16x8*)&Pl[w][lo][hi*8];
        bf16x8 pa1 = *(const bf16x8*)&Pl[w][lo][32 + hi*8];
        #pragma unroll
        for (int nt = 0; nt < 4; ++nt) {
            bf16x8 v0 = *(const bf16x8*)&Vl[nt*16 + lo][hi*8];
            bf16x8 v1 = *(const bf16x8*)&Vl[nt*16 + lo][32 + hi*8];
            acc[nt] = __builtin_amdgcn_mfma_f32_16x16x32_bf16(pa0, v0, acc[nt], 0, 0, 0);
            acc[nt] = __builtin_amdgcn_mfma_f32_16x16x32_bf16(pa1, v1, acc[nt], 0, 0, 0);
        }
        __syncthreads();
    }

    float inv[4];
    #pragma unroll
    for (int r = 0; r < 4; ++r) inv[r] = 1.0f / l_run[r];
    float* op = out + base + (size_t)qbase * HD;
    #pragma unroll
    for (int nt = 0; nt < 4; ++nt)
        #pragma unroll
        for (int r = 0; r < 4; ++r)
            op[(size_t)(hi*4 + r) * HD + nt*16 + lo] = acc[nt][r] * inv[r];
}

extern "C" void kernel_launch(void* const* d_in, const int* in_sizes, int n_in,
                              void* d_out, int out_size, void* d_ws, size_t ws_size,
                              hipStream_t stream) {
    (void)in_sizes; (void)n_in; (void)out_size;
    const float* Q  = (const float*)d_in[0];
    const float* K  = (const float*)d_in[1];
    const float* V  = (const float*)d_in[2];
    const int* mask = (const int*)d_in[3];
    float* out      = (float*)d_out;

    const size_t kv_elems = (size_t)32 * SEQ * HD;          // per tensor
    const size_t need = kv_elems * 2 /*bf16*/ * 2 /*K+V*/;  // 16.78 MB

    if (ws_size >= need) {
        __bf16* Kf = (__bf16*)d_ws;
        __bf16* Vf = Kf + kv_elems;
        hipLaunchKernelGGL(prepass, dim3(NT, 32), dim3(256), 0, stream,
                           K, V, mask, Kf, Vf);
        hipLaunchKernelGGL(attn_fwd5, dim3(1024), dim3(256), 0, stream,
                           Q, Kf, Vf, mask, out);
    } else {
        hipLaunchKernelGGL(attn_fwd_legacy, dim3(SEQ / QB, 32), dim3(256), 0, stream,
                           Q, K, V, mask, out);
    }
}